// Round 2
// baseline (393.527 us; speedup 1.0000x reference)
//
#include <hip/hip_runtime.h>

#define NN 1024
#define CH ((size_t)NN * (size_t)NN)
#define BAND 8

// ---- float4 elementwise helpers ----
__device__ __forceinline__ float4 v_add(float4 a, float4 b) {
    return make_float4(a.x + b.x, a.y + b.y, a.z + b.z, a.w + b.w);
}
__device__ __forceinline__ float4 v_sub(float4 a, float4 b) {
    return make_float4(a.x - b.x, a.y - b.y, a.z - b.z, a.w - b.w);
}
__device__ __forceinline__ float4 v_mul(float4 a, float4 b) {
    return make_float4(a.x * b.x, a.y * b.y, a.z * b.z, a.w * b.w);
}
__device__ __forceinline__ float4 v_fma(float4 a, float4 b, float4 c) {
    return make_float4(fmaf(a.x, b.x, c.x), fmaf(a.y, b.y, c.y),
                       fmaf(a.z, b.z, c.z), fmaf(a.w, b.w, c.w));
}
__device__ __forceinline__ float4 v_fmas(float s, float4 a, float4 c) {
    return make_float4(fmaf(s, a.x, c.x), fmaf(s, a.y, c.y),
                       fmaf(s, a.z, c.z), fmaf(s, a.w, c.w));
}
__device__ __forceinline__ float4 v_scale(float s, float4 a) {
    return make_float4(s * a.x, s * a.y, s * a.z, s * a.w);
}

__device__ __forceinline__ float4 ldf4(const float* p) { return *(const float4*)p; }
__device__ __forceinline__ float2 ldf2(const float* p) { return *(const float2*)p; }

__device__ __forceinline__ int clampr(int r) { return r < 0 ? 0 : (r > NN - 1 ? NN - 1 : r); }

// x-derivatives for 4 px; halo scalars lz,lw (left f4 .z/.w) and rx,ry (right f4 .x/.y).
__device__ __forceinline__ void xder(float lz, float lw, float4 c, float rx, float ry,
                                     int tx, float4& d1, float4& d2) {
    d1.x = 0.5f * (c.y - lw);
    d1.y = 0.5f * (c.z - c.x);
    d1.z = 0.5f * (c.w - c.y);
    d1.w = 0.5f * (rx - c.z);
    d2.x = 0.25f * (c.z - 2.0f * c.x + lz);
    d2.y = 0.25f * (c.w - 2.0f * c.y + lw);
    d2.z = 0.25f * (rx - 2.0f * c.z + c.x);
    d2.w = 0.25f * (ry - 2.0f * c.w + c.y);
    if (tx == 0) {                  // pixels i=0, i=1
        d1.x = c.y - c.x;
        d2.x = 0.5f * c.z - c.y + 0.5f * c.x;
        d2.y = 0.25f * c.w - 0.75f * c.y + 0.5f * c.x;
    } else if (tx == NN / 4 - 1) {  // pixels i=n-2, i=n-1
        d2.z = 0.25f * c.x - 0.75f * c.z + 0.5f * c.w;
        d1.w = c.w - c.z;
        d2.w = 0.5f * c.y - c.z + 0.5f * c.w;
    }
}

__device__ __forceinline__ void xder1(float lw, float4 c, float rx, int tx, float4& d1) {
    d1.x = 0.5f * (c.y - lw);
    d1.y = 0.5f * (c.z - c.x);
    d1.z = 0.5f * (c.w - c.y);
    d1.w = 0.5f * (rx - c.z);
    if (tx == 0)               d1.x = c.y - c.x;
    else if (tx == NN / 4 - 1) d1.w = c.w - c.z;
}

// y-derivatives from ring rows y-2..y+2 (w0..w4). y is block-uniform.
__device__ __forceinline__ void yder(float4 w0, float4 w1, float4 w2, float4 w3, float4 w4,
                                     int y, float4& d1, float4& d2) {
    if (y == 0) {
        d1 = v_sub(w3, w2);
        d2 = v_fmas(0.5f, w4, v_fmas(0.5f, w2, v_scale(-1.0f, w3)));
    } else if (y == 1) {
        d1 = v_scale(0.5f, v_sub(w3, w1));
        d2 = v_fmas(0.25f, w4, v_fmas(-0.75f, w2, v_scale(0.5f, w1)));
    } else if (y == NN - 2) {
        d1 = v_scale(0.5f, v_sub(w3, w1));
        d2 = v_fmas(0.25f, w0, v_fmas(-0.75f, w2, v_scale(0.5f, w3)));
    } else if (y == NN - 1) {
        d1 = v_sub(w2, w1);
        d2 = v_fmas(0.5f, w0, v_fmas(0.5f, w2, v_scale(-1.0f, w1)));
    } else {
        d1 = v_scale(0.5f, v_sub(w3, w1));
        d2 = v_scale(0.25f, v_add(v_sub(w4, v_scale(2.0f, w2)), w0));
    }
}

__device__ __forceinline__ void yder1(float4 p0, float4 p1, float4 p2, int y, float4& d1) {
    if (y == 0)           d1 = v_sub(p2, p1);
    else if (y == NN - 1) d1 = v_sub(p1, p0);
    else                  d1 = v_scale(0.5f, v_sub(p2, p0));
}

// R2 restructure: NO LDS, NO BARRIERS in the hot loop.
// R0/R1 showed 80% stall with VALU=13%, HBM=18%: the LDS x-halo staging convoyed
// all 4 waves of a block at 2 barriers per row, leaving only ~4 independent
// instruction streams per CU to hide ~900-cycle load latency. The x-halo values
// are global data this block loaded 3 iterations ago (L1/L2-resident), so load
// them directly from global (8 small cache-hit loads/row) and let every wave run
// fully asynchronously. Edge threads use clamped dummy offsets; edge formulas
// never consume those values (same guarantee the LDS pads provided).
// Global requests: 7 unique float4/thread/row + 8 cache-hit halo loads.
// XCD swizzle: XCD k owns a contiguous 128-row band per batch.
__global__ __launch_bounds__(256, 4) void physics_residual_kernel(
    const float* __restrict__ fnow, const float* __restrict__ fnext,
    double* __restrict__ part)
{
    const int tx   = threadIdx.x;
    const int flat = blockIdx.x;
    // flat: bits0-2 = xcd, bits3-6 = band-within-xcd (16), bits7-9 = batch
    const int band = ((flat & 7) << 4) | ((flat >> 3) & 15);   // 0..127
    const int b    = flat >> 7;                                 // 0..7
    const int y0   = band * BAND;

    const size_t cb = (size_t)b * 4 * CH + (size_t)tx * 4;
    const float* Up  = fnext + cb;
    const float* Vp  = Up + CH;
    const float* Tp  = Vp + CH;
    const float* Pp  = Tp + CH;
    const float* Unp = fnow + cb;
    const float* Vnp = Unp + CH;
    const float* Tnp = Vnp + CH;

    // Halo offsets relative to this thread's f4 base within the current row.
    // Left halo = previous f4's .z/.w (floats -2,-1); right halo = next f4's
    // .x/.y (floats +4,+5). Edge threads clamp to an in-bounds dummy (value
    // unused by the edge branches of xder/xder1).
    const int lo  = (tx == 0)          ? 0 : -2;   // float2 left
    const int ro  = (tx == NN / 4 - 1) ? 0 : 4;    // float2 right
    const int lop = (tx == 0)          ? 0 : -1;   // scalar left (P)

    // ---- init rings: rows y0-2..y0+2 (clamped low; y0+2 <= 1018 always valid) ----
    float4 U0 = ldf4(Up + (size_t)clampr(y0 - 2) * NN);
    float4 U1 = ldf4(Up + (size_t)clampr(y0 - 1) * NN);
    float4 U2 = ldf4(Up + (size_t)y0 * NN);
    float4 U3 = ldf4(Up + (size_t)(y0 + 1) * NN);
    float4 U4 = ldf4(Up + (size_t)(y0 + 2) * NN);
    float4 V0 = ldf4(Vp + (size_t)clampr(y0 - 2) * NN);
    float4 V1 = ldf4(Vp + (size_t)clampr(y0 - 1) * NN);
    float4 V2 = ldf4(Vp + (size_t)y0 * NN);
    float4 V3 = ldf4(Vp + (size_t)(y0 + 1) * NN);
    float4 V4 = ldf4(Vp + (size_t)(y0 + 2) * NN);
    float4 T0 = ldf4(Tp + (size_t)clampr(y0 - 2) * NN);
    float4 T1 = ldf4(Tp + (size_t)clampr(y0 - 1) * NN);
    float4 T2 = ldf4(Tp + (size_t)y0 * NN);
    float4 T3 = ldf4(Tp + (size_t)(y0 + 1) * NN);
    float4 T4 = ldf4(Tp + (size_t)(y0 + 2) * NN);
    float4 P0 = ldf4(Pp + (size_t)clampr(y0 - 1) * NN);
    float4 P1 = ldf4(Pp + (size_t)y0 * NN);
    float4 P2 = ldf4(Pp + (size_t)(y0 + 1) * NN);

    float acc = 0.0f;

    #pragma unroll 1
    for (int k = 0; k < BAND; ++k) {
        const int y = y0 + k;
        const size_t yc = (size_t)y * NN;

        // ---- the 7 unique global loads for this row (used next iteration) ----
        float4 nU  = ldf4(Up + (size_t)clampr(y + 3) * NN);
        float4 nV  = ldf4(Vp + (size_t)clampr(y + 3) * NN);
        float4 nT  = ldf4(Tp + (size_t)clampr(y + 3) * NN);
        float4 nP  = ldf4(Pp + (size_t)clampr(y + 2) * NN);
        float4 cUn = ldf4(Unp + yc);
        float4 cVn = ldf4(Vnp + yc);
        float4 cTn = ldf4(Tnp + yc);

        // ---- x-halo loads for the CURRENT row: L1/L2 hits (this block fetched
        // these rows as float4s 3 iterations ago). Issued early, used after yder.
        float2 Ul = ldf2(Up + yc + lo);
        float2 Ur = ldf2(Up + yc + ro);
        float2 Vl = ldf2(Vp + yc + lo);
        float2 Vr = ldf2(Vp + yc + ro);
        float2 Tl = ldf2(Tp + yc + lo);
        float2 Tr = ldf2(Tp + yc + ro);
        float  Plw = *(Pp + yc + lop);
        float  Prx = *(Pp + yc + ro);

        // ---- y-derivatives (ring, no memory) ----
        float4 Udy, Udyy, Vdy, Vdyy, Tdy, Tdyy, Pdy;
        yder(U0, U1, U2, U3, U4, y, Udy, Udyy);
        yder(V0, V1, V2, V3, V4, y, Vdy, Vdyy);
        yder(T0, T1, T2, T3, T4, y, Tdy, Tdyy);
        yder1(P0, P1, P2, y, Pdy);

        // ---- x-derivatives ----
        float4 Udx, Udxx, Vdx, Vdxx, Tdx, Tdxx, Pdx;
        xder(Ul.x, Ul.y, U2, Ur.x, Ur.y, tx, Udx, Udxx);
        xder(Vl.x, Vl.y, V2, Vr.x, Vr.y, tx, Vdx, Vdxx);
        xder(Tl.x, Tl.y, T2, Tr.x, Tr.y, tx, Tdx, Tdxx);
        xder1(Plw, P1, Prx, tx, Pdx);

        // ---- residuals ----
        float4 cont = v_add(Udx, Vdy);

        float4 rx4 = v_fmas(100.0f, v_sub(U2, cUn), Pdx);
        rx4 = v_fma(U2, Udx, rx4);
        rx4 = v_fma(cVn, Udy, rx4);
        rx4 = v_fmas(-0.71f, v_add(Udxx, Udyy), rx4);
        rx4 = v_fmas(7.1f, U2, rx4);

        float4 ry4 = v_fmas(100.0f, v_sub(V2, cVn), Pdy);
        ry4 = v_fma(cUn, Vdx, ry4);
        ry4 = v_fma(V2, Vdy, ry4);
        ry4 = v_fmas(-0.71f, v_add(Vdxx, Vdyy), ry4);
        ry4 = v_fmas(-710.0f, T2, ry4);
        ry4 = v_fmas(78.1f, V2, ry4);

        float4 rt4 = v_scale(100.0f, v_sub(T2, cTn));
        rt4 = v_fma(cUn, Tdx, rt4);
        rt4 = v_fma(cVn, Tdy, rt4);
        rt4 = v_fmas(-1.6666666666666667f, v_add(Tdxx, Tdyy), rt4);
        rt4 = v_fmas(-0.1f, T2, rt4);

        float4 sq = v_mul(cont, cont);
        sq = v_fma(rx4, rx4, sq);
        sq = v_fma(ry4, ry4, sq);
        sq = v_fma(rt4, rt4, sq);
        acc += (sq.x + sq.y) + (sq.z + sq.w);

        // ---- shift rings ----
        U0 = U1; U1 = U2; U2 = U3; U3 = U4; U4 = nU;
        V0 = V1; V1 = V2; V2 = V3; V3 = V4; V4 = nV;
        T0 = T1; T1 = T2; T2 = T3; T3 = T4; T4 = nT;
        P0 = P1; P1 = P2; P2 = nP;
    }

    // ---- block reduction -> per-block double partial ----
    double d = (double)acc;
    #pragma unroll
    for (int off = 32; off; off >>= 1) d += __shfl_down(d, off, 64);

    __shared__ double lsum[4];
    const int lane = tx & 63;
    const int wv   = tx >> 6;
    if (lane == 0) lsum[wv] = d;
    __syncthreads();
    if (tx == 0) {
        part[flat] = lsum[0] + lsum[1] + lsum[2] + lsum[3];
    }
}

__global__ __launch_bounds__(1024) void final_reduce_kernel(
    const double* __restrict__ part, int n, float* __restrict__ out)
{
    double s = 0.0;
    for (int i = threadIdx.x; i < n; i += 1024) s += part[i];

    #pragma unroll
    for (int off = 32; off; off >>= 1) s += __shfl_down(s, off, 64);

    __shared__ double lsum[16];
    const int lane = threadIdx.x & 63;
    const int wv   = threadIdx.x >> 6;
    if (lane == 0) lsum[wv] = s;
    __syncthreads();
    if (threadIdx.x == 0) {
        double tot = 0.0;
        #pragma unroll
        for (int i = 0; i < 16; ++i) tot += lsum[i];
        tot *= (1e-4 / 8388608.0);   // BASE_SCALE / mean-count (same for all 4 terms)
        tot = fmin(fmax(tot, 1e-10), 1.0);
        out[0] = (float)tot;
    }
}

extern "C" void kernel_launch(void* const* d_in, const int* in_sizes, int n_in,
                              void* d_out, int out_size, void* d_ws, size_t ws_size,
                              hipStream_t stream) {
    const float* fnow  = (const float*)d_in[0];
    const float* fnext = (const float*)d_in[1];
    double* part = (double*)d_ws;          // 1024 doubles = 8 KiB scratch
    float*  out  = (float*)d_out;

    const int nblk = (NN / BAND) * 8;      // 1024 blocks
    physics_residual_kernel<<<dim3(nblk), 256, 0, stream>>>(fnow, fnext, part);
    final_reduce_kernel<<<1, 1024, 0, stream>>>(part, nblk, out);
}

// Round 3
// 278.034 us; speedup vs baseline: 1.4154x; 1.4154x over previous
//
#include <hip/hip_runtime.h>

#define NN 1024
#define CH ((size_t)NN * (size_t)NN)
#define BAND 8

// ---- float4 elementwise helpers ----
__device__ __forceinline__ float4 v_add(float4 a, float4 b) {
    return make_float4(a.x + b.x, a.y + b.y, a.z + b.z, a.w + b.w);
}
__device__ __forceinline__ float4 v_sub(float4 a, float4 b) {
    return make_float4(a.x - b.x, a.y - b.y, a.z - b.z, a.w - b.w);
}
__device__ __forceinline__ float4 v_mul(float4 a, float4 b) {
    return make_float4(a.x * b.x, a.y * b.y, a.z * b.z, a.w * b.w);
}
__device__ __forceinline__ float4 v_fma(float4 a, float4 b, float4 c) {
    return make_float4(fmaf(a.x, b.x, c.x), fmaf(a.y, b.y, c.y),
                       fmaf(a.z, b.z, c.z), fmaf(a.w, b.w, c.w));
}
__device__ __forceinline__ float4 v_fmas(float s, float4 a, float4 c) {
    return make_float4(fmaf(s, a.x, c.x), fmaf(s, a.y, c.y),
                       fmaf(s, a.z, c.z), fmaf(s, a.w, c.w));
}
__device__ __forceinline__ float4 v_scale(float s, float4 a) {
    return make_float4(s * a.x, s * a.y, s * a.z, s * a.w);
}

__device__ __forceinline__ float4 ldf4(const float* p) { return *(const float4*)p; }
__device__ __forceinline__ float2 ldf2(const float* p) { return *(const float2*)p; }

__device__ __forceinline__ int clampr(int r) { return r < 0 ? 0 : (r > NN - 1 ? NN - 1 : r); }

// x-derivatives for 4 px; halo scalars lz,lw (left f4 .z/.w) and rx,ry (right f4 .x/.y).
__device__ __forceinline__ void xder(float lz, float lw, float4 c, float rx, float ry,
                                     int tx, float4& d1, float4& d2) {
    d1.x = 0.5f * (c.y - lw);
    d1.y = 0.5f * (c.z - c.x);
    d1.z = 0.5f * (c.w - c.y);
    d1.w = 0.5f * (rx - c.z);
    d2.x = 0.25f * (c.z - 2.0f * c.x + lz);
    d2.y = 0.25f * (c.w - 2.0f * c.y + lw);
    d2.z = 0.25f * (rx - 2.0f * c.z + c.x);
    d2.w = 0.25f * (ry - 2.0f * c.w + c.y);
    if (tx == 0) {                  // pixels i=0, i=1
        d1.x = c.y - c.x;
        d2.x = 0.5f * c.z - c.y + 0.5f * c.x;
        d2.y = 0.25f * c.w - 0.75f * c.y + 0.5f * c.x;
    } else if (tx == NN / 4 - 1) {  // pixels i=n-2, i=n-1
        d2.z = 0.25f * c.x - 0.75f * c.z + 0.5f * c.w;
        d1.w = c.w - c.z;
        d2.w = 0.5f * c.y - c.z + 0.5f * c.w;
    }
}

__device__ __forceinline__ void xder1(float lw, float4 c, float rx, int tx, float4& d1) {
    d1.x = 0.5f * (c.y - lw);
    d1.y = 0.5f * (c.z - c.x);
    d1.z = 0.5f * (c.w - c.y);
    d1.w = 0.5f * (rx - c.z);
    if (tx == 0)               d1.x = c.y - c.x;
    else if (tx == NN / 4 - 1) d1.w = c.w - c.z;
}

// y-derivatives from ring rows y-2..y+2 (w0..w4). y is block-uniform.
__device__ __forceinline__ void yder(float4 w0, float4 w1, float4 w2, float4 w3, float4 w4,
                                     int y, float4& d1, float4& d2) {
    if (y == 0) {
        d1 = v_sub(w3, w2);
        d2 = v_fmas(0.5f, w4, v_fmas(0.5f, w2, v_scale(-1.0f, w3)));
    } else if (y == 1) {
        d1 = v_scale(0.5f, v_sub(w3, w1));
        d2 = v_fmas(0.25f, w4, v_fmas(-0.75f, w2, v_scale(0.5f, w1)));
    } else if (y == NN - 2) {
        d1 = v_scale(0.5f, v_sub(w3, w1));
        d2 = v_fmas(0.25f, w0, v_fmas(-0.75f, w2, v_scale(0.5f, w3)));
    } else if (y == NN - 1) {
        d1 = v_sub(w2, w1);
        d2 = v_fmas(0.5f, w0, v_fmas(0.5f, w2, v_scale(-1.0f, w1)));
    } else {
        d1 = v_scale(0.5f, v_sub(w3, w1));
        d2 = v_scale(0.25f, v_add(v_sub(w4, v_scale(2.0f, w2)), w0));
    }
}

__device__ __forceinline__ void yder1(float4 p0, float4 p1, float4 p2, int y, float4& d1) {
    if (y == 0)           d1 = v_sub(p2, p1);
    else if (y == NN - 1) d1 = v_sub(p1, p0);
    else                  d1 = v_scale(0.5f, v_sub(p2, p0));
}

// R3: barrier-free structure from R2 (no LDS, x-halo from cache-hit global loads),
// WITHOUT the __launch_bounds__ occupancy cap. R2's regression was 100% scratch
// spill: the ",4" min-waves clause capped VGPRs (reported 64) below the ~120-130
// this structure needs, producing 278 MB of spill writes + 278 MB of reloads
// (WRITE_SIZE 33KB->278MB, FETCH 151->430MB). Useful fetch was unchanged and
// occupancy/BW rose (19->44%, 1.5->3.3 TB/s) — structure works, cap was the bug.
// Let the allocator take what it needs; zero spill is worth a possible drop to
// 2 blocks/CU (8 independent waves/CU still beat 16 barrier-convoyed ones).
__global__ __launch_bounds__(256) void physics_residual_kernel(
    const float* __restrict__ fnow, const float* __restrict__ fnext,
    double* __restrict__ part)
{
    const int tx   = threadIdx.x;
    const int flat = blockIdx.x;
    // flat: bits0-2 = xcd, bits3-6 = band-within-xcd (16), bits7-9 = batch
    const int band = ((flat & 7) << 4) | ((flat >> 3) & 15);   // 0..127
    const int b    = flat >> 7;                                 // 0..7
    const int y0   = band * BAND;

    const size_t cb = (size_t)b * 4 * CH + (size_t)tx * 4;
    const float* Up  = fnext + cb;
    const float* Vp  = Up + CH;
    const float* Tp  = Vp + CH;
    const float* Pp  = Tp + CH;
    const float* Unp = fnow + cb;
    const float* Vnp = Unp + CH;
    const float* Tnp = Vnp + CH;

    // Halo offsets relative to this thread's f4 base within the current row.
    // Left halo = previous f4's .z/.w (floats -2,-1); right halo = next f4's
    // .x/.y (floats +4,+5). Edge threads clamp to an in-bounds dummy (value
    // unused by the edge branches of xder/xder1).
    const int lo  = (tx == 0)          ? 0 : -2;   // float2 left
    const int ro  = (tx == NN / 4 - 1) ? 0 : 4;    // float2 right
    const int lop = (tx == 0)          ? 0 : -1;   // scalar left (P)

    // ---- init rings: rows y0-2..y0+2 (clamped low; y0+2 <= 1018 always valid) ----
    float4 U0 = ldf4(Up + (size_t)clampr(y0 - 2) * NN);
    float4 U1 = ldf4(Up + (size_t)clampr(y0 - 1) * NN);
    float4 U2 = ldf4(Up + (size_t)y0 * NN);
    float4 U3 = ldf4(Up + (size_t)(y0 + 1) * NN);
    float4 U4 = ldf4(Up + (size_t)(y0 + 2) * NN);
    float4 V0 = ldf4(Vp + (size_t)clampr(y0 - 2) * NN);
    float4 V1 = ldf4(Vp + (size_t)clampr(y0 - 1) * NN);
    float4 V2 = ldf4(Vp + (size_t)y0 * NN);
    float4 V3 = ldf4(Vp + (size_t)(y0 + 1) * NN);
    float4 V4 = ldf4(Vp + (size_t)(y0 + 2) * NN);
    float4 T0 = ldf4(Tp + (size_t)clampr(y0 - 2) * NN);
    float4 T1 = ldf4(Tp + (size_t)clampr(y0 - 1) * NN);
    float4 T2 = ldf4(Tp + (size_t)y0 * NN);
    float4 T3 = ldf4(Tp + (size_t)(y0 + 1) * NN);
    float4 T4 = ldf4(Tp + (size_t)(y0 + 2) * NN);
    float4 P0 = ldf4(Pp + (size_t)clampr(y0 - 1) * NN);
    float4 P1 = ldf4(Pp + (size_t)y0 * NN);
    float4 P2 = ldf4(Pp + (size_t)(y0 + 1) * NN);

    float acc = 0.0f;

    #pragma unroll 1
    for (int k = 0; k < BAND; ++k) {
        const int y = y0 + k;
        const size_t yc = (size_t)y * NN;

        // ---- the 7 unique global loads for this row (used next iteration) ----
        float4 nU  = ldf4(Up + (size_t)clampr(y + 3) * NN);
        float4 nV  = ldf4(Vp + (size_t)clampr(y + 3) * NN);
        float4 nT  = ldf4(Tp + (size_t)clampr(y + 3) * NN);
        float4 nP  = ldf4(Pp + (size_t)clampr(y + 2) * NN);
        float4 cUn = ldf4(Unp + yc);
        float4 cVn = ldf4(Vnp + yc);
        float4 cTn = ldf4(Tnp + yc);

        // ---- x-halo loads for the CURRENT row: L1/L2 hits (this block fetched
        // these rows as float4s 3 iterations ago). Issued early, used after yder.
        float2 Ul = ldf2(Up + yc + lo);
        float2 Ur = ldf2(Up + yc + ro);
        float2 Vl = ldf2(Vp + yc + lo);
        float2 Vr = ldf2(Vp + yc + ro);
        float2 Tl = ldf2(Tp + yc + lo);
        float2 Tr = ldf2(Tp + yc + ro);
        float  Plw = *(Pp + yc + lop);
        float  Prx = *(Pp + yc + ro);

        // ---- y-derivatives (ring, no memory) ----
        float4 Udy, Udyy, Vdy, Vdyy, Tdy, Tdyy, Pdy;
        yder(U0, U1, U2, U3, U4, y, Udy, Udyy);
        yder(V0, V1, V2, V3, V4, y, Vdy, Vdyy);
        yder(T0, T1, T2, T3, T4, y, Tdy, Tdyy);
        yder1(P0, P1, P2, y, Pdy);

        // ---- x-derivatives ----
        float4 Udx, Udxx, Vdx, Vdxx, Tdx, Tdxx, Pdx;
        xder(Ul.x, Ul.y, U2, Ur.x, Ur.y, tx, Udx, Udxx);
        xder(Vl.x, Vl.y, V2, Vr.x, Vr.y, tx, Vdx, Vdxx);
        xder(Tl.x, Tl.y, T2, Tr.x, Tr.y, tx, Tdx, Tdxx);
        xder1(Plw, P1, Prx, tx, Pdx);

        // ---- residuals ----
        float4 cont = v_add(Udx, Vdy);

        float4 rx4 = v_fmas(100.0f, v_sub(U2, cUn), Pdx);
        rx4 = v_fma(U2, Udx, rx4);
        rx4 = v_fma(cVn, Udy, rx4);
        rx4 = v_fmas(-0.71f, v_add(Udxx, Udyy), rx4);
        rx4 = v_fmas(7.1f, U2, rx4);

        float4 ry4 = v_fmas(100.0f, v_sub(V2, cVn), Pdy);
        ry4 = v_fma(cUn, Vdx, ry4);
        ry4 = v_fma(V2, Vdy, ry4);
        ry4 = v_fmas(-0.71f, v_add(Vdxx, Vdyy), ry4);
        ry4 = v_fmas(-710.0f, T2, ry4);
        ry4 = v_fmas(78.1f, V2, ry4);

        float4 rt4 = v_scale(100.0f, v_sub(T2, cTn));
        rt4 = v_fma(cUn, Tdx, rt4);
        rt4 = v_fma(cVn, Tdy, rt4);
        rt4 = v_fmas(-1.6666666666666667f, v_add(Tdxx, Tdyy), rt4);
        rt4 = v_fmas(-0.1f, T2, rt4);

        float4 sq = v_mul(cont, cont);
        sq = v_fma(rx4, rx4, sq);
        sq = v_fma(ry4, ry4, sq);
        sq = v_fma(rt4, rt4, sq);
        acc += (sq.x + sq.y) + (sq.z + sq.w);

        // ---- shift rings ----
        U0 = U1; U1 = U2; U2 = U3; U3 = U4; U4 = nU;
        V0 = V1; V1 = V2; V2 = V3; V3 = V4; V4 = nV;
        T0 = T1; T1 = T2; T2 = T3; T3 = T4; T4 = nT;
        P0 = P1; P1 = P2; P2 = nP;
    }

    // ---- block reduction -> per-block double partial ----
    double d = (double)acc;
    #pragma unroll
    for (int off = 32; off; off >>= 1) d += __shfl_down(d, off, 64);

    __shared__ double lsum[4];
    const int lane = tx & 63;
    const int wv   = tx >> 6;
    if (lane == 0) lsum[wv] = d;
    __syncthreads();
    if (tx == 0) {
        part[flat] = lsum[0] + lsum[1] + lsum[2] + lsum[3];
    }
}

__global__ __launch_bounds__(1024) void final_reduce_kernel(
    const double* __restrict__ part, int n, float* __restrict__ out)
{
    double s = 0.0;
    for (int i = threadIdx.x; i < n; i += 1024) s += part[i];

    #pragma unroll
    for (int off = 32; off; off >>= 1) s += __shfl_down(s, off, 64);

    __shared__ double lsum[16];
    const int lane = threadIdx.x & 63;
    const int wv   = threadIdx.x >> 6;
    if (lane == 0) lsum[wv] = s;
    __syncthreads();
    if (threadIdx.x == 0) {
        double tot = 0.0;
        #pragma unroll
        for (int i = 0; i < 16; ++i) tot += lsum[i];
        tot *= (1e-4 / 8388608.0);   // BASE_SCALE / mean-count (same for all 4 terms)
        tot = fmin(fmax(tot, 1e-10), 1.0);
        out[0] = (float)tot;
    }
}

extern "C" void kernel_launch(void* const* d_in, const int* in_sizes, int n_in,
                              void* d_out, int out_size, void* d_ws, size_t ws_size,
                              hipStream_t stream) {
    const float* fnow  = (const float*)d_in[0];
    const float* fnext = (const float*)d_in[1];
    double* part = (double*)d_ws;          // 1024 doubles = 8 KiB scratch
    float*  out  = (float*)d_out;

    const int nblk = (NN / BAND) * 8;      // 1024 blocks
    physics_residual_kernel<<<dim3(nblk), 256, 0, stream>>>(fnow, fnext, part);
    final_reduce_kernel<<<1, 1024, 0, stream>>>(part, nblk, out);
}